// Round 1
// baseline (204.288 us; speedup 1.0000x reference)
//
#include <hip/hip_runtime.h>
#include <hip/hip_bf16.h>

// Problem constants (match reference: B=32, T=4096, E=256, L=T/2, THRESHOLD=0)
constexpr int B = 32;
constexpr int T = 4096;
constexpr int E = 256;
constexpr int L = T / 2;          // 2048
constexpr int E4 = E / 4;         // 64 float4 per row

// ---------------------------------------------------------------------------
// Kernel 1: per-batch compaction scan.
// One block (256 threads) per batch. Each thread owns 8 contiguous timesteps.
// Produces srcmap[b*L + j] = source timestep of j-th kept row, and count[b].
// ---------------------------------------------------------------------------
__global__ __launch_bounds__(256) void scan_kernel(
    const float* __restrict__ x,
    const float* __restrict__ pad_amt,
    int* __restrict__ srcmap,
    int* __restrict__ count)
{
    const int b   = blockIdx.x;
    const int tid = threadIdx.x;          // 0..255
    const float scale = 1.0f + fabsf(pad_amt[0]);

    // Each thread: 8 contiguous timesteps [tid*8, tid*8+8)
    int keep[8];
    int s = 0;
#pragma unroll
    for (int i = 0; i < 8; ++i) {
        const int t = tid * 8 + i;
        const float pad = x[(size_t)(b * T + t) * E] * scale;  // channel 0
        keep[i] = (pad < 0.0f) ? 1 : 0;
        s += keep[i];
    }

    // Wave-level inclusive scan of s (wave = 64 lanes)
    const int lane = tid & 63;
    const int wave = tid >> 6;            // 0..3
    int inc = s;
#pragma unroll
    for (int off = 1; off < 64; off <<= 1) {
        int n = __shfl_up(inc, off, 64);
        if (lane >= off) inc += n;
    }

    __shared__ int wsum[4];
    if (lane == 63) wsum[wave] = inc;
    __syncthreads();

    int wbase = 0;
#pragma unroll
    for (int w = 0; w < 3; ++w)
        if (w < wave) wbase += wsum[w];

    const int excl = wbase + inc - s;     // exclusive prefix for this thread

    int run = excl;
#pragma unroll
    for (int i = 0; i < 8; ++i) {
        if (keep[i]) {
            srcmap[b * L + run] = tid * 8 + i;
            ++run;
        }
    }

    if (tid == 0)
        count[b] = wsum[0] + wsum[1] + wsum[2] + wsum[3];
}

// ---------------------------------------------------------------------------
// Kernel 2: coalesced gather + zero-fill.
// One float4 per thread; 64 threads cover one output row (256 floats).
// ---------------------------------------------------------------------------
__global__ __launch_bounds__(256) void gather_kernel(
    const float* __restrict__ x,
    const float* __restrict__ pad_amt,
    const int* __restrict__ srcmap,
    const int* __restrict__ count,
    float* __restrict__ out)
{
    const int g   = blockIdx.x * 256 + threadIdx.x;  // global float4 index
    const int row = g >> 6;                           // output row: b*L + j
    const int d   = g & 63;                           // float4 index in row
    const int b   = row >> 11;                        // row / L (L = 2048)
    const int j   = row & (L - 1);                    // row % L

    float4 v;
    if (j < count[b]) {
        const int t = srcmap[row];
        const float4* src = reinterpret_cast<const float4*>(x)
                          + (size_t)(b * T + t) * E4;
        v = src[d];
        if (d == 0)
            v.x *= (1.0f + fabsf(pad_amt[0]));        // pad value in channel 0
    } else {
        v = make_float4(0.0f, 0.0f, 0.0f, 0.0f);      // base (THRESHOLD = 0)
    }
    reinterpret_cast<float4*>(out)[g] = v;
}

// ---------------------------------------------------------------------------
extern "C" void kernel_launch(void* const* d_in, const int* in_sizes, int n_in,
                              void* d_out, int out_size, void* d_ws, size_t ws_size,
                              hipStream_t stream)
{
    const float* x       = reinterpret_cast<const float*>(d_in[0]);
    const float* pad_amt = reinterpret_cast<const float*>(d_in[1]);
    // d_in[2] = clipped_length (always L = 2048, compile-time constant)

    // Workspace layout: [count: B ints][pad to 256B][srcmap: B*L ints]
    int* count  = reinterpret_cast<int*>(d_ws);
    int* srcmap = reinterpret_cast<int*>(d_ws) + 64;  // 256-byte offset

    scan_kernel<<<B, 256, 0, stream>>>(x, pad_amt, srcmap, count);

    const int total_f4 = B * L * E4;                  // 4,194,304
    gather_kernel<<<total_f4 / 256, 256, 0, stream>>>(x, pad_amt, srcmap, count,
                                                      reinterpret_cast<float*>(d_out));
}

// Round 2
// 203.533 us; speedup vs baseline: 1.0037x; 1.0037x over previous
//
#include <hip/hip_runtime.h>
#include <hip/hip_bf16.h>

// Problem constants (reference: B=32, T=4096, E=256, L=T/2, THRESHOLD=0)
constexpr int B  = 32;
constexpr int T  = 4096;
constexpr int E  = 256;
constexpr int L  = T / 2;     // 2048
constexpr int E4 = E / 4;     // 64 float4 per row

// ---------------------------------------------------------------------------
// Kernel 1: per-batch compaction scan.
// keep(t) <=> x[b,t,0] < 0  (scale = 1+|p| > 0 cannot flip the sign, and
// x==0 is not < 0 either before or after scaling — exact equivalence).
// One block of 1024 threads per batch, 2 timesteps per thread.
// Writes srcmap[b*L + j] = t of j-th kept row; tail filled with -1 sentinel.
// ---------------------------------------------------------------------------
__global__ __launch_bounds__(1024) void scan_kernel(
    const float* __restrict__ x,
    int* __restrict__ srcmap)
{
    const int b   = blockIdx.x;
    const int tid = threadIdx.x;              // 0..1023
    const int t0  = tid * 2;

    const size_t base = (size_t)b * T * E;
    const float a0 = x[base + (size_t)t0 * E];        // channel 0
    const float a1 = x[base + (size_t)(t0 + 1) * E];
    const int k0 = (a0 < 0.0f) ? 1 : 0;
    const int k1 = (a1 < 0.0f) ? 1 : 0;
    const int s  = k0 + k1;

    // Wave-level inclusive scan (wave = 64)
    const int lane = tid & 63;
    const int wave = tid >> 6;                // 0..15
    int inc = s;
#pragma unroll
    for (int off = 1; off < 64; off <<= 1) {
        int n = __shfl_up(inc, off, 64);
        if (lane >= off) inc += n;
    }

    __shared__ int wsum[16];
    if (lane == 63) wsum[wave] = inc;
    __syncthreads();

    int wbase = 0, total = 0;
#pragma unroll
    for (int w = 0; w < 16; ++w) {
        const int v = wsum[w];
        if (w < wave) wbase += v;
        total += v;
    }

    const int excl = wbase + inc - s;         // #keeps with t < t0
    int* __restrict__ sm = srcmap + b * L;
    if (k0) sm[excl]      = t0;
    if (k1) sm[excl + k0] = t0 + 1;

    // Sentinel tail: rows [total, L) produce zeros in the gather.
    for (int k = total + tid; k < L; k += 1024)
        sm[k] = -1;
}

// ---------------------------------------------------------------------------
// Kernel 2: coalesced gather + zero-fill.
// 256 threads/block = 16 output rows/block; each thread does 4 float4.
// Instruction i: 16-lane group reads/writes a contiguous 256 B segment.
// ---------------------------------------------------------------------------
__global__ __launch_bounds__(256) void gather_kernel(
    const float* __restrict__ x,
    const float* __restrict__ pad_amt,
    const int* __restrict__ srcmap,
    float* __restrict__ out)
{
    const int r   = blockIdx.x * 16 + (threadIdx.x >> 4);  // output row b*L+j
    const int l16 = threadIdx.x & 15;                      // 0..15
    const int t   = srcmap[r];                             // -1 => zero row
    const int b   = r >> 11;                               // r / L

    float4 v0, v1, v2, v3;
    if (t >= 0) {
        const float4* __restrict__ s =
            reinterpret_cast<const float4*>(x) + ((size_t)(b * T) + t) * E4;
        v0 = s[ 0 + l16];
        v1 = s[16 + l16];
        v2 = s[32 + l16];
        v3 = s[48 + l16];
        if (l16 == 0)
            v0.x *= (1.0f + fabsf(pad_amt[0]));            // scaled pad, ch 0
    } else {
        v0 = v1 = v2 = v3 = make_float4(0.f, 0.f, 0.f, 0.f);
    }

    float4* __restrict__ o = reinterpret_cast<float4*>(out) + (size_t)r * E4;
    o[ 0 + l16] = v0;
    o[16 + l16] = v1;
    o[32 + l16] = v2;
    o[48 + l16] = v3;
}

// ---------------------------------------------------------------------------
extern "C" void kernel_launch(void* const* d_in, const int* in_sizes, int n_in,
                              void* d_out, int out_size, void* d_ws, size_t ws_size,
                              hipStream_t stream)
{
    const float* x       = reinterpret_cast<const float*>(d_in[0]);
    const float* pad_amt = reinterpret_cast<const float*>(d_in[1]);
    // d_in[2] = clipped_length (compile-time constant L = 2048)

    int* srcmap = reinterpret_cast<int*>(d_ws);            // B*L ints = 256 KiB

    scan_kernel<<<B, 1024, 0, stream>>>(x, srcmap);

    gather_kernel<<<(B * L) / 16, 256, 0, stream>>>(
        x, pad_amt, srcmap, reinterpret_cast<float*>(d_out));
}